// Round 21
// baseline (1116.952 us; speedup 1.0000x reference)
//
#include <hip/hip_runtime.h>
#include <hip/hip_fp16.h>
#include <math.h>

#define BN_ROWS 16384   // B*N
#define DIM 512
#define FF 2048
#define LAYERS 4
#define NSEQ 512
#define BATCH 32

typedef _Float16 f16;
typedef __attribute__((ext_vector_type(8))) _Float16 f16x8;
typedef __attribute__((ext_vector_type(4))) _Float16 f16x4;
typedef __attribute__((ext_vector_type(4))) float f32x4;
typedef __attribute__((ext_vector_type(16))) float f32x16;
typedef unsigned long long u64;

__device__ __forceinline__ f32x4 mfma_f16(f16x8 a, f16x8 b, f32x4 c) {
    return __builtin_amdgcn_mfma_f32_16x16x32_f16(a, b, c, 0, 0, 0);
}
__device__ __forceinline__ f32x16 mfma32(f16x8 a, f16x8 b, f32x16 c) {
    return __builtin_amdgcn_mfma_f32_32x32x16_f16(a, b, c, 0, 0, 0);
}
__device__ __forceinline__ unsigned pk2u(float x, float y) {
    auto t = __builtin_amdgcn_cvt_pkrtz(x, y);   // 2 x f16 packed
    return *reinterpret_cast<unsigned*>(&t);
}
__device__ __forceinline__ void gload_lds16(const f16* g, f16* l) {
    __builtin_amdgcn_global_load_lds(
        (const __attribute__((address_space(1))) unsigned int*)g,
        (__attribute__((address_space(3))) unsigned int*)l, 16, 0, 0);
}

// ---------------- weight prep (single fp16 plane) ----------------
__global__ __launch_bounds__(256)
void pack_qkv(const float* __restrict__ Wq, const float* __restrict__ Wk,
              const float* __restrict__ Wv, f16* __restrict__ oh) {
    size_t i = (size_t)blockIdx.x * 256 + threadIdx.x;
    int d = i & 511;
    size_t rr = i >> 9;
    int row = (int)(rr % 1536);
    int lay = (int)(rr / 1536);
    int which = row >> 9, hh = (row >> 6) & 7, k = row & 63;
    const float* W = which == 0 ? Wq : which == 1 ? Wk : Wv;
    oh[i] = (f16)W[(((size_t)lay * 8 + hh) * 512 + d) * 64 + k];
}

__global__ __launch_bounds__(256)
void transpose_w(const float* __restrict__ in, f16* __restrict__ oh, int R, int C) {
    size_t i = (size_t)blockIdx.x * 256 + threadIdx.x;
    int r = (int)(i % R);
    size_t t = i / R;
    int c = (int)(t % C);
    int lay = (int)(t / C);
    oh[i] = (f16)in[((size_t)lay * R + r) * C + c];
}

// mask [B][N][N] int -> bits [B][N][8] u64
__global__ __launch_bounds__(256)
void pack_mask(const int* __restrict__ mask, u64* __restrict__ pm) {
    int wid = (blockIdx.x * 256 + threadIdx.x) >> 6;
    int lane = threadIdx.x & 63;
    for (int i = 0; i < 64; i++) {
        size_t word = (size_t)wid * 64 + i;
        u64 bal = __ballot(mask[word * 64 + lane] != 0);
        if (lane == 0) pm[word] = bal;
    }
}

// ---------------- embed (writes f16 trunk) ----------------
__global__ __launch_bounds__(512)
void embed_kernel(const float* __restrict__ x, const float* __restrict__ We,
                  const float* __restrict__ be, f16* __restrict__ h16) {
    int row = blockIdx.x, d = threadIdx.x;
    const float* xr = x + (size_t)row * 8;
    float acc = be[d];
#pragma unroll
    for (int c = 0; c < 8; c++) acc += xr[c] * We[c * DIM + d];
    h16[(size_t)row * DIM + d] = (f16)acc;
}

// ---------------- fp16 MFMA GEMM: 128x128 tile, 512 threads / 8 waves ----------------
// launch_bounds(512,6): cap VGPR at 85 so 3 blocks/CU fit (LDS 48KB allows 3).
// OUT=1: bias+relu -> f16 O0 (coalesced store via dead-LDS half-tiles)
// OUT=2: QKV split (Q pre-scaled by 0.125*log2e ->O0, K->O1 — both coalesced via LDS;
//        V transposed ->O2 direct)
// OUT=3: residual+BN-stats on f16 trunk (direct scatter — measured faster than LDS)
template<int OUT>
__global__ __launch_bounds__(512, 6)
void gemm_f16(const f16* __restrict__ A, const f16* __restrict__ Bt,
              const float* __restrict__ bias,
              void* __restrict__ O0, void* __restrict__ O1, void* __restrict__ O2,
              int M, int N, int K) {
    __shared__ f16 As[3][4096];   // [buf][128 rows][32 k], XOR-swizzled chunks
    __shared__ f16 Bs[3][4096];
    const int gx = gridDim.x;
    const int nwg = gx * gridDim.y;
    const int id = blockIdx.y * gx + blockIdx.x;
    const int chunk = nwg >> 3;
    const int sid = (id & 7) * chunk + (id >> 3);
    const int row0 = (sid / gx) * 128, col0 = (sid % gx) * 128;

    const int tid = threadIdx.x, l = tid & 63, w = tid >> 6;
    const int wr = w & 1, wc = w >> 1;            // row half, col quarter
    const int fr = l & 15, fq = l >> 4;
    const int srow = tid >> 2;                    // staging row 0..127
    const int skg = ((tid & 3) ^ ((tid >> 3) & 3)) * 8;   // pre-swizzled source chunk
    const int fqs8 = (fq ^ ((fr >> 1) & 3)) * 8;          // matching read swizzle

    f32x4 acc[4][2] = {};
    const f16* Ab = A + (size_t)(row0 + srow) * K + skg;
    const f16* Bb = Bt + (size_t)(col0 + srow) * K + skg;
    const int nt = K >> 5;

    auto stage = [&](int buf, int k0) {
        gload_lds16(Ab + k0, &As[buf][w * 512]);
        gload_lds16(Bb + k0, &Bs[buf][w * 512]);
    };

    stage(0, 0);
    stage(1, 32);

    for (int kt = 0; kt < nt; kt++) {
        const int buf = kt % 3;
        if (kt + 1 < nt) asm volatile("s_waitcnt vmcnt(2)" ::: "memory");
        else             asm volatile("s_waitcnt vmcnt(0)" ::: "memory");
        __builtin_amdgcn_s_barrier();
        __builtin_amdgcn_sched_barrier(0);
        if (kt + 2 < nt) stage((kt + 2) % 3, (kt + 2) * 32);
        f16x8 a[4], b[2];
#pragma unroll
        for (int i = 0; i < 4; i++)
            a[i] = *(const f16x8*)&As[buf][(wr * 64 + i * 16 + fr) * 32 + fqs8];
#pragma unroll
        for (int j = 0; j < 2; j++)
            b[j] = *(const f16x8*)&Bs[buf][(wc * 32 + j * 16 + fr) * 32 + fqs8];
#pragma unroll
        for (int i = 0; i < 4; i++)
#pragma unroll
            for (int j = 0; j < 2; j++)
                acc[i][j] = mfma_f16(a[i], b[j], acc[i][j]);
    }

    // epilogue helpers (coalesced half-tile path): thread covers row srow6 of the
    // half, chunks c0/c1 (16B each); XOR-swizzle p = chunk ^ (row&15) both sides.
    f16* Bs16 = &Bs[0][0];
    const int srow6 = tid >> 3, cb = tid & 7;
    const int c0 = cb, c1 = 8 + cb;
    const int g0 = c0 ^ (srow6 & 15), g1 = c1 ^ (srow6 & 15);

    if (OUT == 1) {
        f16* C = (f16*)O0;
#pragma unroll
        for (int hf = 0; hf < 2; hf++) {
            __syncthreads();   // prior LDS use done
            if (wr == hf) {
#pragma unroll
                for (int j = 0; j < 2; j++) {
                    int lc = wc * 32 + j * 16 + fr;
                    float bv = bias[col0 + lc];
#pragma unroll
                    for (int i = 0; i < 4; i++)
#pragma unroll
                        for (int r = 0; r < 4; r++) {
                            int lr = i * 16 + fq * 4 + r;
                            int p = (lc >> 3) ^ (lr & 15);
                            Bs16[lr * 128 + p * 8 + (lc & 7)] =
                                (f16)fmaxf(acc[i][j][r] + bv, 0.f);
                        }
                }
            }
            __syncthreads();
            size_t grow = (size_t)(row0 + hf * 64 + srow6) * N + col0;
            *(f16x8*)&C[grow + g0 * 8] = *(const f16x8*)&Bs16[srow6 * 128 + c0 * 8];
            *(f16x8*)&C[grow + g1 * 8] = *(const f16x8*)&Bs16[srow6 * 128 + c1 * 8];
        }
    } else if (OUT == 2) {
        const float SCQ = 0.18033688011112042f;   // 0.125 * log2(e), folded into Q
        f16* Qo = (f16*)O0; f16* Ko = (f16*)O1; f16* Vo = (f16*)O2;
        if (col0 < 1024) {
            // Q or K block: coalesced store via dead-LDS half-tiles
            bool isQ = col0 < 512;
            f16* dst = isQ ? Qo : Ko;
            float sc = isQ ? SCQ : 1.0f;
            int ccol0 = col0 & 511;
#pragma unroll
            for (int hf = 0; hf < 2; hf++) {
                __syncthreads();
                if (wr == hf) {
#pragma unroll
                    for (int j = 0; j < 2; j++) {
                        int lc = wc * 32 + j * 16 + fr;
#pragma unroll
                        for (int i = 0; i < 4; i++)
#pragma unroll
                            for (int r = 0; r < 4; r++) {
                                int lr = i * 16 + fq * 4 + r;
                                int p = (lc >> 3) ^ (lr & 15);
                                Bs16[lr * 128 + p * 8 + (lc & 7)] =
                                    (f16)(acc[i][j][r] * sc);
                            }
                    }
                }
                __syncthreads();
                size_t grow = (size_t)(row0 + hf * 64 + srow6) * 512 + ccol0;
                *(f16x8*)&dst[grow + g0 * 8] = *(const f16x8*)&Bs16[srow6 * 128 + c0 * 8];
                *(f16x8*)&dst[grow + g1 * 8] = *(const f16x8*)&Bs16[srow6 * 128 + c1 * 8];
            }
        } else {
            // V block: transposed write (already 8B vectorized)
#pragma unroll
            for (int j = 0; j < 2; j++) {
                int gcol = col0 + wc * 32 + j * 16 + fr;
                int hh = (gcol - 1024) >> 6, v = gcol & 63;
#pragma unroll
                for (int i = 0; i < 4; i++) {
                    int gr = row0 + wr * 64 + i * 16 + fq * 4;
                    int b = gr >> 9, n = gr & 511;
                    f16x4 sv;
#pragma unroll
                    for (int r = 0; r < 4; r++) sv[r] = (f16)acc[i][j][r];
                    *(f16x4*)&Vo[(((size_t)b * 8 + hh) * 64 + v) * 512 + n] = sv;
                }
            }
        }
    } else {   // OUT == 3: f16 trunk residual + stats (direct scatter)
        f16* hres = (f16*)O0;
        float* st  = (float*)O1;
#pragma unroll
        for (int j = 0; j < 2; j++) {
            int gcol = col0 + wc * 32 + j * 16 + fr;
            float bv = bias ? bias[gcol] : 0.f;
            float csum = 0.f, csq = 0.f;
#pragma unroll
            for (int i = 0; i < 4; i++) {
                int gr = row0 + wr * 64 + i * 16 + fq * 4;
#pragma unroll
                for (int r = 0; r < 4; r++) {
                    size_t idx = (size_t)(gr + r) * N + gcol;
                    float v = acc[i][j][r] + bv + (float)hres[idx];
                    hres[idx] = (f16)v;
                    csum += v; csq += v * v;
                }
            }
            csum += __shfl_down(csum, 32, 64); csum += __shfl_down(csum, 16, 64);
            csq  += __shfl_down(csq,  32, 64); csq  += __shfl_down(csq,  16, 64);
            if (fq == 0) {
                atomicAdd(&st[gcol], csum);
                atomicAdd(&st[gcol + 512], csq);
            }
        }
    }
}

// ---------------- flash attention: 8 waves / 256 q-rows per block ----------------
__global__ __launch_bounds__(512, 4)
void attn_flash(const f16* __restrict__ Q, const f16* __restrict__ Kg,
                const f16* __restrict__ Vt, const u64* __restrict__ pmask,
                f16* __restrict__ attf) {
    int id = blockIdx.x;
    int wgid = (id & 7) * 64 + (id >> 3);   // bijective XCD swizzle (512 = 8*64)
    int qc = wgid & 1;
    int gid = wgid >> 1;
    int b = gid & 31, hd = gid >> 5;

    __shared__ f16 Kl[2][4096];     // [cg 0..7][row 0..63] x 8 f16
    __shared__ f16 Vl[2][4096];

    const int tid = threadIdx.x, w = tid >> 6, l = tid & 63;
    const int q = l & 31, hi = l >> 5;

    const int brow = qc * 256 + w * 32;
    const size_t qrow = ((size_t)b * NSEQ + brow + q) * DIM + hd * 64;
    f16x8 qb[4];
#pragma unroll
    for (int c16 = 0; c16 < 4; c16++)
        qb[c16] = *(const f16x8*)(Q + qrow + c16 * 16 + hi * 8);

    const f16* ksrc = Kg + (size_t)b * NSEQ * DIM + hd * 64;   // row stride DIM
    const f16* vsrc = Vt + ((size_t)b * 8 + hd) * 64 * 512;    // row stride 512
    const u64* mrowq = pmask + ((size_t)b * NSEQ + brow + q) * 8;

    const int srw = tid & 63, scg = tid >> 6;   // staging row / col-group

    const float THR = 11.0f;    // P <= 2^11, f16-safe
    float mu = -1e30f;
    f32x16 O0 = {}, O1 = {}, S1 = {};

    f16x8 vones;
#pragma unroll
    for (int i = 0; i < 8; i++) vones[i] = (f16)1.0f;

    gload_lds16(ksrc + (size_t)srw * DIM + scg * 8, &Kl[0][tid * 8]);
    gload_lds16(vsrc + (size_t)srw * 512 + scg * 8, &Vl[0][tid * 8]);

    u64 bits = mrowq[0];

    for (int c = 0; c < 8; c++) {
        const int buf = c & 1;
        __syncthreads();   // stage(c) landed; prior reads of buf^1 done
        if (c < 7) {
            const int n1 = (c + 1) * 64;
            gload_lds16(ksrc + (size_t)(n1 + srw) * DIM + scg * 8, &Kl[buf ^ 1][tid * 8]);
            gload_lds16(vsrc + (size_t)srw * 512 + n1 + scg * 8,   &Vl[buf ^ 1][tid * 8]);
        }

        f32x16 ps0 = {}, ps1 = {};
        __builtin_amdgcn_s_setprio(1);
#pragma unroll
        for (int c16 = 0; c16 < 4; c16++) {
            f16x8 kb0 = *(const f16x8*)&Kl[buf][((c16 * 2 + hi) * 64 + q) * 8];
            f16x8 kb1 = *(const f16x8*)&Kl[buf][((c16 * 2 + hi) * 64 + 32 + q) * 8];
            ps0 = mfma32(kb0, qb[c16], ps0);
            ps1 = mfma32(kb1, qb[c16], ps1);
        }
        __builtin_amdgcn_s_setprio(0);

        unsigned blo = (unsigned)bits, bhi = (unsigned)(bits >> 32);
        if (c < 7) bits = mrowq[c + 1];   // prefetch next mask word

        float lm = fmaxf(ps0[0], ps1[0]);
#pragma unroll
        for (int r = 1; r < 16; r++) lm = fmaxf(lm, fmaxf(ps0[r], ps1[r]));
        if (__any(lm > mu + THR)) {
            float other = __shfl_xor(lm, 32, 64);
            float mn = fmaxf(mu, fmaxf(lm, other));
            float sc = exp2f(mu - mn);
            mu = mn;
            S1 *= sc; O0 *= sc; O1 *= sc;
        }

        float p0[16], p1[16];
#pragma unroll
        for (int r = 0; r < 16; r++) {
            int n0 = (r & 3) + 8 * (r >> 2) + 4 * hi;
            float e0 = exp2f(ps0[r] - mu);
            float e1 = exp2f(ps1[r] - mu);
            unsigned k0 = ((blo >> n0) & 1u) - 1u;   // 0xFFFFFFFF keep, 0 zero
            unsigned k1 = ((bhi >> n0) & 1u) - 1u;
            p0[r] = __uint_as_float(__float_as_uint(e0) & k0);
            p1[r] = __uint_as_float(__float_as_uint(e1) & k1);
        }

        f16x8 PA[2][2];
#pragma unroll
        for (int ntile = 0; ntile < 2; ntile++) {
            const float* p = ntile ? p1 : p0;
#pragma unroll
            for (int m = 0; m < 2; m++) {
                unsigned a0 = pk2u(p[m * 8 + 0], p[m * 8 + 1]);
                unsigned b0 = pk2u(p[m * 8 + 4], p[m * 8 + 5]);
                auto s0 = __builtin_amdgcn_permlane32_swap(a0, b0, false, false);
                unsigned a1 = pk2u(p[m * 8 + 2], p[m * 8 + 3]);
                unsigned b1 = pk2u(p[m * 8 + 6], p[m * 8 + 7]);
                auto s1 = __builtin_amdgcn_permlane32_swap(a1, b1, false, false);
                unsigned wbuf[4] = {(unsigned)s0[0], (unsigned)s1[0],
                                    (unsigned)s0[1], (unsigned)s1[1]};
                PA[ntile][m] = *reinterpret_cast<f16x8*>(wbuf);
            }
        }

        __builtin_amdgcn_s_setprio(1);
#pragma unroll
        for (int ntile = 0; ntile < 2; ntile++)
#pragma unroll
            for (int m = 0; m < 2; m++) {
                f16x8 pa = PA[ntile][m];
                S1 = mfma32(vones, pa, S1);
                int cg = ntile * 4 + m * 2 + hi;
                f16x8 v0 = *(const f16x8*)&Vl[buf][(cg * 64 + q) * 8];
                f16x8 v1 = *(const f16x8*)&Vl[buf][(cg * 64 + 32 + q) * 8];
                O0 = mfma32(v0, pa, O0);
                O1 = mfma32(v1, pa, O1);
            }
        __builtin_amdgcn_s_setprio(0);
    }

    float inv = 1.f / S1[0];
    f16* orow = attf + ((size_t)b * NSEQ + brow + q) * DIM + hd * 64;
#pragma unroll
    for (int r = 0; r < 16; r += 2) {
        int v = (r & 3) + 8 * (r >> 2) + 4 * hi;
        unsigned w0 = pk2u(O0[r] * inv, O0[r + 1] * inv);
        *(unsigned*)(orow + v) = w0;
        unsigned w1 = pk2u(O1[r] * inv, O1[r + 1] * inv);
        *(unsigned*)(orow + 32 + v) = w1;
    }
}

// ---------------- BN apply on f16 trunk (vectorized x8) ----------------
__global__ __launch_bounds__(256)
void bn_apply(f16* __restrict__ h16, const float* __restrict__ sums,
              const float* __restrict__ g, const float* __restrict__ bt,
              float* __restrict__ outp) {
    size_t i8 = (size_t)blockIdx.x * 256 + threadIdx.x;
    size_t idx = i8 * 8;
    int c = (int)(idx & (DIM - 1));
    f16x8 hv = *(f16x8*)&h16[idx];
    float o[8];
    const float invn = 1.f / BN_ROWS;
#pragma unroll
    for (int j = 0; j < 8; j++) {
        float mu = sums[c + j] * invn;
        float var = sums[DIM + c + j] * invn - mu * mu;
        o[j] = ((float)hv[j] - mu) * rsqrtf(var + 1e-5f) * g[c + j] + bt[c + j];
    }
    f16x8 s;
#pragma unroll
    for (int j = 0; j < 8; j++) s[j] = (f16)o[j];
    *(f16x8*)&h16[idx] = s;
    if (outp) {
        *(float4*)&outp[idx]     = (float4){o[0], o[1], o[2], o[3]};
        *(float4*)&outp[idx + 4] = (float4){o[4], o[5], o[6], o[7]};
    }
}

// ---------------- mean over n ----------------
__global__ __launch_bounds__(512)
void mean_kernel(const float* __restrict__ src, float* __restrict__ out2) {
    int b = blockIdx.x, seg = blockIdx.y, d = threadIdx.x;
    float acc = 0.f;
    for (int n = seg * 64; n < seg * 64 + 64; n++)
        acc += src[((size_t)b * NSEQ + n) * DIM + d];
    atomicAdd(&out2[b * DIM + d], acc * (1.f / NSEQ));
}

extern "C" void kernel_launch(void* const* d_in, const int* in_sizes, int n_in,
                              void* d_out, int out_size, void* d_ws, size_t ws_size,
                              hipStream_t stream) {
    const float* x   = (const float*)d_in[0];
    const int*   mask= (const int*)d_in[1];
    const float* We  = (const float*)d_in[2];
    const float* be  = (const float*)d_in[3];
    const float* Wq  = (const float*)d_in[4];
    const float* Wk  = (const float*)d_in[5];
    const float* Wv  = (const float*)d_in[6];
    const float* Wo  = (const float*)d_in[7];
    const float* g1  = (const float*)d_in[8];
    const float* bt1 = (const float*)d_in[9];
    const float* g2  = (const float*)d_in[10];
    const float* bt2 = (const float*)d_in[11];
    const float* W1  = (const float*)d_in[12];
    const float* bf1 = (const float*)d_in[13];
    const float* W2  = (const float*)d_in[14];
    const float* bf2 = (const float*)d_in[15];
    float* out = (float*)d_out;

    const size_t MiB = 1ull << 20;
    const size_t M1 = (size_t)BN_ROWS * DIM;
    char* base = (char*)d_ws;
    f16*   h16   = (f16*)base;                      // 0-16 MiB (f16 trunk)
    f16*   Qf    = (f16*)(base + 16 * MiB);
    f16*   Kf    = (f16*)(base + 32 * MiB);
    f16*   Vt    = (f16*)(base + 48 * MiB);
    f16*   attf  = (f16*)(base + 64 * MiB);
    f16*   ffh   = (f16*)(base + 16 * MiB);         // 64 MiB, reuses Qf..attf (dead by FFN)
    float* stats = (float*)(base + 80 * MiB);       // 8 slots x 1024 floats = 32 KiB
    u64*   pmask = (u64*)(base + 80 * MiB + 65536); // 1 MiB
    f16*   wqkv  = (f16*)(base + 82 * MiB);         // 12.6 MiB
    f16*   wo    = wqkv + (size_t)4 * 1536 * 512;   // 2.1
    f16*   w1t   = wo   + (size_t)4 * 512 * 512;    // 8.4
    f16*   w2t   = w1t  + (size_t)4 * 2048 * 512;   // 8.4

    pack_qkv<<<dim3(4 * 1536 * 512 / 256), dim3(256), 0, stream>>>(Wq, Wk, Wv, wqkv);
    transpose_w<<<dim3(4 * 512 * 512 / 256), dim3(256), 0, stream>>>(Wo, wo, 512, 512);
    transpose_w<<<dim3(4 * 512 * 2048 / 256), dim3(256), 0, stream>>>(W1, w1t, 512, 2048);
    transpose_w<<<dim3(4 * 2048 * 512 / 256), dim3(256), 0, stream>>>(W2, w2t, 2048, 512);
    pack_mask<<<dim3(512), dim3(256), 0, stream>>>(mask, pmask);
    hipMemsetAsync(stats, 0, 8 * 1024 * sizeof(float), stream);   // all BN slots, once
    hipMemsetAsync(out + M1, 0, BATCH * DIM * sizeof(float), stream);

    embed_kernel<<<dim3(BN_ROWS), dim3(512), 0, stream>>>(x, We, be, h16);

    for (int l = 0; l < LAYERS; l++) {
        float* st1 = stats + (size_t)(l * 2 + 0) * 1024;
        float* st2 = stats + (size_t)(l * 2 + 1) * 1024;

        gemm_f16<2><<<dim3(1536 / 128, 128), dim3(512), 0, stream>>>(
            h16, wqkv + (size_t)l * 1536 * 512, nullptr, Qf, Kf, Vt,
            BN_ROWS, 1536, 512);

        attn_flash<<<dim3(512), dim3(512), 0, stream>>>(Qf, Kf, Vt, pmask, attf);

        gemm_f16<3><<<dim3(512 / 128, 128), dim3(512), 0, stream>>>(
            attf, wo + (size_t)l * 512 * 512, nullptr, h16, st1, nullptr,
            BN_ROWS, 512, 512);
        bn_apply<<<dim3(M1 / 2048), dim3(256), 0, stream>>>(
            h16, st1, g1 + l * DIM, bt1 + l * DIM, nullptr);

        gemm_f16<1><<<dim3(FF / 128, BN_ROWS / 128), dim3(512), 0, stream>>>(
            h16, w1t + (size_t)l * FF * DIM, bf1 + (size_t)l * FF,
            ffh, nullptr, nullptr, BN_ROWS, FF, DIM);
        gemm_f16<3><<<dim3(512 / 128, 128), dim3(512), 0, stream>>>(
            ffh, w2t + (size_t)l * DIM * FF, bf2 + (size_t)l * DIM,
            h16, st2, nullptr, BN_ROWS, 512, FF);

        float* outp = (l == LAYERS - 1) ? out : nullptr;
        bn_apply<<<dim3(M1 / 2048), dim3(256), 0, stream>>>(
            h16, st2, g2 + l * DIM, bt2 + l * DIM, outp);
    }

    mean_kernel<<<dim3(BATCH, 8), dim3(512), 0, stream>>>(out, out + M1);
}

// Round 22
// 1103.240 us; speedup vs baseline: 1.0124x; 1.0124x over previous
//
#include <hip/hip_runtime.h>
#include <hip/hip_fp16.h>
#include <math.h>

#define BN_ROWS 16384   // B*N
#define DIM 512
#define FF 2048
#define LAYERS 4
#define NSEQ 512
#define BATCH 32

typedef _Float16 f16;
typedef __attribute__((ext_vector_type(8))) _Float16 f16x8;
typedef __attribute__((ext_vector_type(4))) _Float16 f16x4;
typedef __attribute__((ext_vector_type(4))) float f32x4;
typedef __attribute__((ext_vector_type(16))) float f32x16;
typedef unsigned long long u64;

__device__ __forceinline__ f32x4 mfma_f16(f16x8 a, f16x8 b, f32x4 c) {
    return __builtin_amdgcn_mfma_f32_16x16x32_f16(a, b, c, 0, 0, 0);
}
__device__ __forceinline__ f32x16 mfma32(f16x8 a, f16x8 b, f32x16 c) {
    return __builtin_amdgcn_mfma_f32_32x32x16_f16(a, b, c, 0, 0, 0);
}
__device__ __forceinline__ unsigned pk2u(float x, float y) {
    auto t = __builtin_amdgcn_cvt_pkrtz(x, y);   // 2 x f16 packed
    return *reinterpret_cast<unsigned*>(&t);
}
__device__ __forceinline__ void gload_lds16(const f16* g, f16* l) {
    __builtin_amdgcn_global_load_lds(
        (const __attribute__((address_space(1))) unsigned int*)g,
        (__attribute__((address_space(3))) unsigned int*)l, 16, 0, 0);
}

// ---------------- weight prep (single fp16 plane) ----------------
__global__ __launch_bounds__(256)
void pack_qkv(const float* __restrict__ Wq, const float* __restrict__ Wk,
              const float* __restrict__ Wv, f16* __restrict__ oh) {
    size_t i = (size_t)blockIdx.x * 256 + threadIdx.x;
    int d = i & 511;
    size_t rr = i >> 9;
    int row = (int)(rr % 1536);
    int lay = (int)(rr / 1536);
    int which = row >> 9, hh = (row >> 6) & 7, k = row & 63;
    const float* W = which == 0 ? Wq : which == 1 ? Wk : Wv;
    oh[i] = (f16)W[(((size_t)lay * 8 + hh) * 512 + d) * 64 + k];
}

__global__ __launch_bounds__(256)
void transpose_w(const float* __restrict__ in, f16* __restrict__ oh, int R, int C) {
    size_t i = (size_t)blockIdx.x * 256 + threadIdx.x;
    int r = (int)(i % R);
    size_t t = i / R;
    int c = (int)(t % C);
    int lay = (int)(t / C);
    oh[i] = (f16)in[((size_t)lay * R + r) * C + c];
}

// mask [B][N][N] int -> bits [B][N][8] u64
__global__ __launch_bounds__(256)
void pack_mask(const int* __restrict__ mask, u64* __restrict__ pm) {
    int wid = (blockIdx.x * 256 + threadIdx.x) >> 6;
    int lane = threadIdx.x & 63;
    for (int i = 0; i < 64; i++) {
        size_t word = (size_t)wid * 64 + i;
        u64 bal = __ballot(mask[word * 64 + lane] != 0);
        if (lane == 0) pm[word] = bal;
    }
}

// ---------------- embed (writes f16 trunk) ----------------
__global__ __launch_bounds__(512)
void embed_kernel(const float* __restrict__ x, const float* __restrict__ We,
                  const float* __restrict__ be, f16* __restrict__ h16) {
    int row = blockIdx.x, d = threadIdx.x;
    const float* xr = x + (size_t)row * 8;
    float acc = be[d];
#pragma unroll
    for (int c = 0; c < 8; c++) acc += xr[c] * We[c * DIM + d];
    h16[(size_t)row * DIM + d] = (f16)acc;
}

// ---------------- fp16 MFMA GEMM: 128x128 tile, 512 threads / 8 waves ----------------
// launch_bounds(512,6): cap VGPR at 85 so 3 blocks/CU fit (LDS 48KB allows 3).
// OUT=1: bias+relu -> f16 O0 (coalesced store via dead-LDS half-tiles; measured -11us/disp)
// OUT=2: QKV split, direct stores (LDS variant measured +65us total -> reverted)
// OUT=3: residual+BN-stats, direct scatter (LDS variant measured +23us total -> reverted)
template<int OUT>
__global__ __launch_bounds__(512, 6)
void gemm_f16(const f16* __restrict__ A, const f16* __restrict__ Bt,
              const float* __restrict__ bias,
              void* __restrict__ O0, void* __restrict__ O1, void* __restrict__ O2,
              int M, int N, int K) {
    __shared__ f16 As[3][4096];   // [buf][128 rows][32 k], XOR-swizzled chunks
    __shared__ f16 Bs[3][4096];
    const int gx = gridDim.x;
    const int nwg = gx * gridDim.y;
    const int id = blockIdx.y * gx + blockIdx.x;
    const int chunk = nwg >> 3;
    const int sid = (id & 7) * chunk + (id >> 3);
    const int row0 = (sid / gx) * 128, col0 = (sid % gx) * 128;

    const int tid = threadIdx.x, l = tid & 63, w = tid >> 6;
    const int wr = w & 1, wc = w >> 1;            // row half, col quarter
    const int fr = l & 15, fq = l >> 4;
    const int srow = tid >> 2;                    // staging row 0..127
    const int skg = ((tid & 3) ^ ((tid >> 3) & 3)) * 8;   // pre-swizzled source chunk
    const int fqs8 = (fq ^ ((fr >> 1) & 3)) * 8;          // matching read swizzle

    f32x4 acc[4][2] = {};
    const f16* Ab = A + (size_t)(row0 + srow) * K + skg;
    const f16* Bb = Bt + (size_t)(col0 + srow) * K + skg;
    const int nt = K >> 5;

    auto stage = [&](int buf, int k0) {
        gload_lds16(Ab + k0, &As[buf][w * 512]);
        gload_lds16(Bb + k0, &Bs[buf][w * 512]);
    };

    stage(0, 0);
    stage(1, 32);

    for (int kt = 0; kt < nt; kt++) {
        const int buf = kt % 3;
        if (kt + 1 < nt) asm volatile("s_waitcnt vmcnt(2)" ::: "memory");
        else             asm volatile("s_waitcnt vmcnt(0)" ::: "memory");
        __builtin_amdgcn_s_barrier();
        __builtin_amdgcn_sched_barrier(0);
        if (kt + 2 < nt) stage((kt + 2) % 3, (kt + 2) * 32);
        f16x8 a[4], b[2];
#pragma unroll
        for (int i = 0; i < 4; i++)
            a[i] = *(const f16x8*)&As[buf][(wr * 64 + i * 16 + fr) * 32 + fqs8];
#pragma unroll
        for (int j = 0; j < 2; j++)
            b[j] = *(const f16x8*)&Bs[buf][(wc * 32 + j * 16 + fr) * 32 + fqs8];
#pragma unroll
        for (int i = 0; i < 4; i++)
#pragma unroll
            for (int j = 0; j < 2; j++)
                acc[i][j] = mfma_f16(a[i], b[j], acc[i][j]);
    }

    if (OUT == 1) {
        // coalesced store via dead-LDS half-tiles (XOR p = chunk ^ (row&15))
        f16* C = (f16*)O0;
        f16* Bs16 = &Bs[0][0];
        const int srow6 = tid >> 3, cb = tid & 7;
        const int c0 = cb, c1 = 8 + cb;
        const int g0 = c0 ^ (srow6 & 15), g1 = c1 ^ (srow6 & 15);
#pragma unroll
        for (int hf = 0; hf < 2; hf++) {
            __syncthreads();   // prior LDS use done
            if (wr == hf) {
#pragma unroll
                for (int j = 0; j < 2; j++) {
                    int lc = wc * 32 + j * 16 + fr;
                    float bv = bias[col0 + lc];
#pragma unroll
                    for (int i = 0; i < 4; i++)
#pragma unroll
                        for (int r = 0; r < 4; r++) {
                            int lr = i * 16 + fq * 4 + r;
                            int p = (lc >> 3) ^ (lr & 15);
                            Bs16[lr * 128 + p * 8 + (lc & 7)] =
                                (f16)fmaxf(acc[i][j][r] + bv, 0.f);
                        }
                }
            }
            __syncthreads();
            size_t grow = (size_t)(row0 + hf * 64 + srow6) * N + col0;
            *(f16x8*)&C[grow + g0 * 8] = *(const f16x8*)&Bs16[srow6 * 128 + c0 * 8];
            *(f16x8*)&C[grow + g1 * 8] = *(const f16x8*)&Bs16[srow6 * 128 + c1 * 8];
        }
    } else if (OUT == 2) {
        const float SCQ = 0.18033688011112042f;   // 0.125 * log2(e), folded into Q
        f16* Qo = (f16*)O0; f16* Ko = (f16*)O1; f16* Vo = (f16*)O2;
#pragma unroll
        for (int j = 0; j < 2; j++) {
            int gcol = col0 + wc * 32 + j * 16 + fr;
            if (gcol < 1024) {
                bool isQ = gcol < 512;
                f16* dst = isQ ? Qo : Ko;
                float sc = isQ ? SCQ : 1.0f;
                int cc = gcol & 511;
#pragma unroll
                for (int i = 0; i < 4; i++) {
                    int gr = row0 + wr * 64 + i * 16 + fq * 4;
#pragma unroll
                    for (int r = 0; r < 4; r++)
                        dst[(size_t)(gr + r) * 512 + cc] = (f16)(acc[i][j][r] * sc);
                }
            } else {
                int hh = (gcol - 1024) >> 6, v = gcol & 63;
#pragma unroll
                for (int i = 0; i < 4; i++) {
                    int gr = row0 + wr * 64 + i * 16 + fq * 4;
                    int b = gr >> 9, n = gr & 511;
                    f16x4 sv;
#pragma unroll
                    for (int r = 0; r < 4; r++) sv[r] = (f16)acc[i][j][r];
                    *(f16x4*)&Vo[(((size_t)b * 8 + hh) * 64 + v) * 512 + n] = sv;
                }
            }
        }
    } else {   // OUT == 3: f16 trunk residual + stats (direct scatter)
        f16* hres = (f16*)O0;
        float* st  = (float*)O1;
#pragma unroll
        for (int j = 0; j < 2; j++) {
            int gcol = col0 + wc * 32 + j * 16 + fr;
            float bv = bias ? bias[gcol] : 0.f;
            float csum = 0.f, csq = 0.f;
#pragma unroll
            for (int i = 0; i < 4; i++) {
                int gr = row0 + wr * 64 + i * 16 + fq * 4;
#pragma unroll
                for (int r = 0; r < 4; r++) {
                    size_t idx = (size_t)(gr + r) * N + gcol;
                    float v = acc[i][j][r] + bv + (float)hres[idx];
                    hres[idx] = (f16)v;
                    csum += v; csq += v * v;
                }
            }
            csum += __shfl_down(csum, 32, 64); csum += __shfl_down(csum, 16, 64);
            csq  += __shfl_down(csq,  32, 64); csq  += __shfl_down(csq,  16, 64);
            if (fq == 0) {
                atomicAdd(&st[gcol], csum);
                atomicAdd(&st[gcol + 512], csq);
            }
        }
    }
}

// ---------------- flash attention: 8 waves / 256 q-rows per block ----------------
__global__ __launch_bounds__(512, 4)
void attn_flash(const f16* __restrict__ Q, const f16* __restrict__ Kg,
                const f16* __restrict__ Vt, const u64* __restrict__ pmask,
                f16* __restrict__ attf) {
    int id = blockIdx.x;
    int wgid = (id & 7) * 64 + (id >> 3);   // bijective XCD swizzle (512 = 8*64)
    int qc = wgid & 1;
    int gid = wgid >> 1;
    int b = gid & 31, hd = gid >> 5;

    __shared__ f16 Kl[2][4096];     // [cg 0..7][row 0..63] x 8 f16
    __shared__ f16 Vl[2][4096];

    const int tid = threadIdx.x, w = tid >> 6, l = tid & 63;
    const int q = l & 31, hi = l >> 5;

    const int brow = qc * 256 + w * 32;
    const size_t qrow = ((size_t)b * NSEQ + brow + q) * DIM + hd * 64;
    f16x8 qb[4];
#pragma unroll
    for (int c16 = 0; c16 < 4; c16++)
        qb[c16] = *(const f16x8*)(Q + qrow + c16 * 16 + hi * 8);

    const f16* ksrc = Kg + (size_t)b * NSEQ * DIM + hd * 64;   // row stride DIM
    const f16* vsrc = Vt + ((size_t)b * 8 + hd) * 64 * 512;    // row stride 512
    const u64* mrowq = pmask + ((size_t)b * NSEQ + brow + q) * 8;

    const int srw = tid & 63, scg = tid >> 6;   // staging row / col-group

    const float THR = 11.0f;    // P <= 2^11, f16-safe
    float mu = -1e30f;
    f32x16 O0 = {}, O1 = {}, S1 = {};

    f16x8 vones;
#pragma unroll
    for (int i = 0; i < 8; i++) vones[i] = (f16)1.0f;

    gload_lds16(ksrc + (size_t)srw * DIM + scg * 8, &Kl[0][tid * 8]);
    gload_lds16(vsrc + (size_t)srw * 512 + scg * 8, &Vl[0][tid * 8]);

    u64 bits = mrowq[0];

    for (int c = 0; c < 8; c++) {
        const int buf = c & 1;
        __syncthreads();   // stage(c) landed; prior reads of buf^1 done
        if (c < 7) {
            const int n1 = (c + 1) * 64;
            gload_lds16(ksrc + (size_t)(n1 + srw) * DIM + scg * 8, &Kl[buf ^ 1][tid * 8]);
            gload_lds16(vsrc + (size_t)srw * 512 + n1 + scg * 8,   &Vl[buf ^ 1][tid * 8]);
        }

        f32x16 ps0 = {}, ps1 = {};
        __builtin_amdgcn_s_setprio(1);
#pragma unroll
        for (int c16 = 0; c16 < 4; c16++) {
            f16x8 kb0 = *(const f16x8*)&Kl[buf][((c16 * 2 + hi) * 64 + q) * 8];
            f16x8 kb1 = *(const f16x8*)&Kl[buf][((c16 * 2 + hi) * 64 + 32 + q) * 8];
            ps0 = mfma32(kb0, qb[c16], ps0);
            ps1 = mfma32(kb1, qb[c16], ps1);
        }
        __builtin_amdgcn_s_setprio(0);

        unsigned blo = (unsigned)bits, bhi = (unsigned)(bits >> 32);
        if (c < 7) bits = mrowq[c + 1];   // prefetch next mask word

        float lm = fmaxf(ps0[0], ps1[0]);
#pragma unroll
        for (int r = 1; r < 16; r++) lm = fmaxf(lm, fmaxf(ps0[r], ps1[r]));
        if (__any(lm > mu + THR)) {
            float other = __shfl_xor(lm, 32, 64);
            float mn = fmaxf(mu, fmaxf(lm, other));
            float sc = exp2f(mu - mn);
            mu = mn;
            S1 *= sc; O0 *= sc; O1 *= sc;
        }

        float p0[16], p1[16];
#pragma unroll
        for (int r = 0; r < 16; r++) {
            int n0 = (r & 3) + 8 * (r >> 2) + 4 * hi;
            float e0 = exp2f(ps0[r] - mu);
            float e1 = exp2f(ps1[r] - mu);
            unsigned k0 = ((blo >> n0) & 1u) - 1u;   // 0xFFFFFFFF keep, 0 zero
            unsigned k1 = ((bhi >> n0) & 1u) - 1u;
            p0[r] = __uint_as_float(__float_as_uint(e0) & k0);
            p1[r] = __uint_as_float(__float_as_uint(e1) & k1);
        }

        f16x8 PA[2][2];
#pragma unroll
        for (int ntile = 0; ntile < 2; ntile++) {
            const float* p = ntile ? p1 : p0;
#pragma unroll
            for (int m = 0; m < 2; m++) {
                unsigned a0 = pk2u(p[m * 8 + 0], p[m * 8 + 1]);
                unsigned b0 = pk2u(p[m * 8 + 4], p[m * 8 + 5]);
                auto s0 = __builtin_amdgcn_permlane32_swap(a0, b0, false, false);
                unsigned a1 = pk2u(p[m * 8 + 2], p[m * 8 + 3]);
                unsigned b1 = pk2u(p[m * 8 + 6], p[m * 8 + 7]);
                auto s1 = __builtin_amdgcn_permlane32_swap(a1, b1, false, false);
                unsigned wbuf[4] = {(unsigned)s0[0], (unsigned)s1[0],
                                    (unsigned)s0[1], (unsigned)s1[1]};
                PA[ntile][m] = *reinterpret_cast<f16x8*>(wbuf);
            }
        }

        __builtin_amdgcn_s_setprio(1);
#pragma unroll
        for (int ntile = 0; ntile < 2; ntile++)
#pragma unroll
            for (int m = 0; m < 2; m++) {
                f16x8 pa = PA[ntile][m];
                S1 = mfma32(vones, pa, S1);
                int cg = ntile * 4 + m * 2 + hi;
                f16x8 v0 = *(const f16x8*)&Vl[buf][(cg * 64 + q) * 8];
                f16x8 v1 = *(const f16x8*)&Vl[buf][(cg * 64 + 32 + q) * 8];
                O0 = mfma32(v0, pa, O0);
                O1 = mfma32(v1, pa, O1);
            }
        __builtin_amdgcn_s_setprio(0);
    }

    float inv = 1.f / S1[0];
    f16* orow = attf + ((size_t)b * NSEQ + brow + q) * DIM + hd * 64;
#pragma unroll
    for (int r = 0; r < 16; r += 2) {
        int v = (r & 3) + 8 * (r >> 2) + 4 * hi;
        unsigned w0 = pk2u(O0[r] * inv, O0[r + 1] * inv);
        *(unsigned*)(orow + v) = w0;
        unsigned w1 = pk2u(O1[r] * inv, O1[r + 1] * inv);
        *(unsigned*)(orow + 32 + v) = w1;
    }
}

// ---------------- BN apply on f16 trunk (vectorized x8) ----------------
__global__ __launch_bounds__(256)
void bn_apply(f16* __restrict__ h16, const float* __restrict__ sums,
              const float* __restrict__ g, const float* __restrict__ bt,
              float* __restrict__ outp) {
    size_t i8 = (size_t)blockIdx.x * 256 + threadIdx.x;
    size_t idx = i8 * 8;
    int c = (int)(idx & (DIM - 1));
    f16x8 hv = *(f16x8*)&h16[idx];
    float o[8];
    const float invn = 1.f / BN_ROWS;
#pragma unroll
    for (int j = 0; j < 8; j++) {
        float mu = sums[c + j] * invn;
        float var = sums[DIM + c + j] * invn - mu * mu;
        o[j] = ((float)hv[j] - mu) * rsqrtf(var + 1e-5f) * g[c + j] + bt[c + j];
    }
    f16x8 s;
#pragma unroll
    for (int j = 0; j < 8; j++) s[j] = (f16)o[j];
    *(f16x8*)&h16[idx] = s;
    if (outp) {
        *(float4*)&outp[idx]     = (float4){o[0], o[1], o[2], o[3]};
        *(float4*)&outp[idx + 4] = (float4){o[4], o[5], o[6], o[7]};
    }
}

// ---------------- mean over n ----------------
__global__ __launch_bounds__(512)
void mean_kernel(const float* __restrict__ src, float* __restrict__ out2) {
    int b = blockIdx.x, seg = blockIdx.y, d = threadIdx.x;
    float acc = 0.f;
    for (int n = seg * 64; n < seg * 64 + 64; n++)
        acc += src[((size_t)b * NSEQ + n) * DIM + d];
    atomicAdd(&out2[b * DIM + d], acc * (1.f / NSEQ));
}

extern "C" void kernel_launch(void* const* d_in, const int* in_sizes, int n_in,
                              void* d_out, int out_size, void* d_ws, size_t ws_size,
                              hipStream_t stream) {
    const float* x   = (const float*)d_in[0];
    const int*   mask= (const int*)d_in[1];
    const float* We  = (const float*)d_in[2];
    const float* be  = (const float*)d_in[3];
    const float* Wq  = (const float*)d_in[4];
    const float* Wk  = (const float*)d_in[5];
    const float* Wv  = (const float*)d_in[6];
    const float* Wo  = (const float*)d_in[7];
    const float* g1  = (const float*)d_in[8];
    const float* bt1 = (const float*)d_in[9];
    const float* g2  = (const float*)d_in[10];
    const float* bt2 = (const float*)d_in[11];
    const float* W1  = (const float*)d_in[12];
    const float* bf1 = (const float*)d_in[13];
    const float* W2  = (const float*)d_in[14];
    const float* bf2 = (const float*)d_in[15];
    float* out = (float*)d_out;

    const size_t MiB = 1ull << 20;
    const size_t M1 = (size_t)BN_ROWS * DIM;
    char* base = (char*)d_ws;
    f16*   h16   = (f16*)base;                      // 0-16 MiB (f16 trunk)
    f16*   Qf    = (f16*)(base + 16 * MiB);
    f16*   Kf    = (f16*)(base + 32 * MiB);
    f16*   Vt    = (f16*)(base + 48 * MiB);
    f16*   attf  = (f16*)(base + 64 * MiB);
    f16*   ffh   = (f16*)(base + 16 * MiB);         // 64 MiB, reuses Qf..attf (dead by FFN)
    float* stats = (float*)(base + 80 * MiB);       // 8 slots x 1024 floats = 32 KiB
    u64*   pmask = (u64*)(base + 80 * MiB + 65536); // 1 MiB
    f16*   wqkv  = (f16*)(base + 82 * MiB);         // 12.6 MiB
    f16*   wo    = wqkv + (size_t)4 * 1536 * 512;   // 2.1
    f16*   w1t   = wo   + (size_t)4 * 512 * 512;    // 8.4
    f16*   w2t   = w1t  + (size_t)4 * 2048 * 512;   // 8.4

    pack_qkv<<<dim3(4 * 1536 * 512 / 256), dim3(256), 0, stream>>>(Wq, Wk, Wv, wqkv);
    transpose_w<<<dim3(4 * 512 * 512 / 256), dim3(256), 0, stream>>>(Wo, wo, 512, 512);
    transpose_w<<<dim3(4 * 512 * 2048 / 256), dim3(256), 0, stream>>>(W1, w1t, 512, 2048);
    transpose_w<<<dim3(4 * 2048 * 512 / 256), dim3(256), 0, stream>>>(W2, w2t, 2048, 512);
    pack_mask<<<dim3(512), dim3(256), 0, stream>>>(mask, pmask);
    hipMemsetAsync(stats, 0, 8 * 1024 * sizeof(float), stream);   // all BN slots, once
    hipMemsetAsync(out + M1, 0, BATCH * DIM * sizeof(float), stream);

    embed_kernel<<<dim3(BN_ROWS), dim3(512), 0, stream>>>(x, We, be, h16);

    for (int l = 0; l < LAYERS; l++) {
        float* st1 = stats + (size_t)(l * 2 + 0) * 1024;
        float* st2 = stats + (size_t)(l * 2 + 1) * 1024;

        gemm_f16<2><<<dim3(1536 / 128, 128), dim3(512), 0, stream>>>(
            h16, wqkv + (size_t)l * 1536 * 512, nullptr, Qf, Kf, Vt,
            BN_ROWS, 1536, 512);

        attn_flash<<<dim3(512), dim3(512), 0, stream>>>(Qf, Kf, Vt, pmask, attf);

        gemm_f16<3><<<dim3(512 / 128, 128), dim3(512), 0, stream>>>(
            attf, wo + (size_t)l * 512 * 512, nullptr, h16, st1, nullptr,
            BN_ROWS, 512, 512);
        bn_apply<<<dim3(M1 / 2048), dim3(256), 0, stream>>>(
            h16, st1, g1 + l * DIM, bt1 + l * DIM, nullptr);

        gemm_f16<1><<<dim3(FF / 128, BN_ROWS / 128), dim3(512), 0, stream>>>(
            h16, w1t + (size_t)l * FF * DIM, bf1 + (size_t)l * FF,
            ffh, nullptr, nullptr, BN_ROWS, FF, DIM);
        gemm_f16<3><<<dim3(512 / 128, 128), dim3(512), 0, stream>>>(
            ffh, w2t + (size_t)l * DIM * FF, bf2 + (size_t)l * DIM,
            h16, st2, nullptr, BN_ROWS, 512, FF);

        float* outp = (l == LAYERS - 1) ? out : nullptr;
        bn_apply<<<dim3(M1 / 2048), dim3(256), 0, stream>>>(
            h16, st2, g2 + l * DIM, bt2 + l * DIM, outp);
    }

    mean_kernel<<<dim3(BATCH, 8), dim3(512), 0, stream>>>(out, out + M1);
}

// Round 23
// 1071.967 us; speedup vs baseline: 1.0420x; 1.0292x over previous
//
#include <hip/hip_runtime.h>
#include <hip/hip_fp16.h>
#include <math.h>

#define BN_ROWS 16384   // B*N
#define DIM 512
#define FF 2048
#define LAYERS 4
#define NSEQ 512
#define BATCH 32

typedef _Float16 f16;
typedef __attribute__((ext_vector_type(8))) _Float16 f16x8;
typedef __attribute__((ext_vector_type(4))) _Float16 f16x4;
typedef __attribute__((ext_vector_type(4))) float f32x4;
typedef __attribute__((ext_vector_type(16))) float f32x16;
typedef unsigned long long u64;

__device__ __forceinline__ f32x4 mfma_f16(f16x8 a, f16x8 b, f32x4 c) {
    return __builtin_amdgcn_mfma_f32_16x16x32_f16(a, b, c, 0, 0, 0);
}
__device__ __forceinline__ f32x16 mfma32(f16x8 a, f16x8 b, f32x16 c) {
    return __builtin_amdgcn_mfma_f32_32x32x16_f16(a, b, c, 0, 0, 0);
}
__device__ __forceinline__ unsigned pk2u(float x, float y) {
    auto t = __builtin_amdgcn_cvt_pkrtz(x, y);   // 2 x f16 packed
    return *reinterpret_cast<unsigned*>(&t);
}
__device__ __forceinline__ void gload_lds16(const f16* g, f16* l) {
    __builtin_amdgcn_global_load_lds(
        (const __attribute__((address_space(1))) unsigned int*)g,
        (__attribute__((address_space(3))) unsigned int*)l, 16, 0, 0);
}

// ---------------- weight prep (single fp16 plane) ----------------
__global__ __launch_bounds__(256)
void pack_qkv(const float* __restrict__ Wq, const float* __restrict__ Wk,
              const float* __restrict__ Wv, f16* __restrict__ oh) {
    size_t i = (size_t)blockIdx.x * 256 + threadIdx.x;
    int d = i & 511;
    size_t rr = i >> 9;
    int row = (int)(rr % 1536);
    int lay = (int)(rr / 1536);
    int which = row >> 9, hh = (row >> 6) & 7, k = row & 63;
    const float* W = which == 0 ? Wq : which == 1 ? Wk : Wv;
    oh[i] = (f16)W[(((size_t)lay * 8 + hh) * 512 + d) * 64 + k];
}

__global__ __launch_bounds__(256)
void transpose_w(const float* __restrict__ in, f16* __restrict__ oh, int R, int C) {
    size_t i = (size_t)blockIdx.x * 256 + threadIdx.x;
    int r = (int)(i % R);
    size_t t = i / R;
    int c = (int)(t % C);
    int lay = (int)(t / C);
    oh[i] = (f16)in[((size_t)lay * R + r) * C + c];
}

// mask [B][N][N] int -> bits [B][N][8] u64
__global__ __launch_bounds__(256)
void pack_mask(const int* __restrict__ mask, u64* __restrict__ pm) {
    int wid = (blockIdx.x * 256 + threadIdx.x) >> 6;
    int lane = threadIdx.x & 63;
    for (int i = 0; i < 64; i++) {
        size_t word = (size_t)wid * 64 + i;
        u64 bal = __ballot(mask[word * 64 + lane] != 0);
        if (lane == 0) pm[word] = bal;
    }
}

// ---------------- embed (writes f16 trunk) ----------------
__global__ __launch_bounds__(512)
void embed_kernel(const float* __restrict__ x, const float* __restrict__ We,
                  const float* __restrict__ be, f16* __restrict__ h16) {
    int row = blockIdx.x, d = threadIdx.x;
    const float* xr = x + (size_t)row * 8;
    float acc = be[d];
#pragma unroll
    for (int c = 0; c < 8; c++) acc += xr[c] * We[c * DIM + d];
    h16[(size_t)row * DIM + d] = (f16)acc;
}

// ---------------- fp16 MFMA GEMM: 128x128 tile, 512 threads / 8 waves ----------------
// launch_bounds(512,6): cap VGPR at 85 so 3 blocks/CU fit (LDS 48KB allows 3).
// OUT=1: bias+relu -> f16 O0 (coalesced store via dead-LDS half-tiles)
// OUT=2: QKV split (Q pre-scaled by 0.125*log2e ->O0, K->O1; V transposed ->O2)
// OUT=3: residual+BN-stats on f16 trunk (coalesced read+write via dead-LDS half-tiles)
// NOTE: OUT3-LDS measured best on END-TO-END total (1075 vs 1103 direct) even though
// per-dispatch rocprof time looks worse — downstream bn_apply locality benefits.
template<int OUT>
__global__ __launch_bounds__(512, 6)
void gemm_f16(const f16* __restrict__ A, const f16* __restrict__ Bt,
              const float* __restrict__ bias,
              void* __restrict__ O0, void* __restrict__ O1, void* __restrict__ O2,
              int M, int N, int K) {
    __shared__ f16 As[3][4096];   // [buf][128 rows][32 k], XOR-swizzled chunks
    __shared__ f16 Bs[3][4096];
    const int gx = gridDim.x;
    const int nwg = gx * gridDim.y;
    const int id = blockIdx.y * gx + blockIdx.x;
    const int chunk = nwg >> 3;
    const int sid = (id & 7) * chunk + (id >> 3);
    const int row0 = (sid / gx) * 128, col0 = (sid % gx) * 128;

    const int tid = threadIdx.x, l = tid & 63, w = tid >> 6;
    const int wr = w & 1, wc = w >> 1;            // row half, col quarter
    const int fr = l & 15, fq = l >> 4;
    const int srow = tid >> 2;                    // staging row 0..127
    const int skg = ((tid & 3) ^ ((tid >> 3) & 3)) * 8;   // pre-swizzled source chunk
    const int fqs8 = (fq ^ ((fr >> 1) & 3)) * 8;          // matching read swizzle

    f32x4 acc[4][2] = {};
    const f16* Ab = A + (size_t)(row0 + srow) * K + skg;
    const f16* Bb = Bt + (size_t)(col0 + srow) * K + skg;
    const int nt = K >> 5;

    auto stage = [&](int buf, int k0) {
        gload_lds16(Ab + k0, &As[buf][w * 512]);
        gload_lds16(Bb + k0, &Bs[buf][w * 512]);
    };

    stage(0, 0);
    stage(1, 32);

    for (int kt = 0; kt < nt; kt++) {
        const int buf = kt % 3;
        if (kt + 1 < nt) asm volatile("s_waitcnt vmcnt(2)" ::: "memory");
        else             asm volatile("s_waitcnt vmcnt(0)" ::: "memory");
        __builtin_amdgcn_s_barrier();
        __builtin_amdgcn_sched_barrier(0);
        if (kt + 2 < nt) stage((kt + 2) % 3, (kt + 2) * 32);
        f16x8 a[4], b[2];
#pragma unroll
        for (int i = 0; i < 4; i++)
            a[i] = *(const f16x8*)&As[buf][(wr * 64 + i * 16 + fr) * 32 + fqs8];
#pragma unroll
        for (int j = 0; j < 2; j++)
            b[j] = *(const f16x8*)&Bs[buf][(wc * 32 + j * 16 + fr) * 32 + fqs8];
#pragma unroll
        for (int i = 0; i < 4; i++)
#pragma unroll
            for (int j = 0; j < 2; j++)
                acc[i][j] = mfma_f16(a[i], b[j], acc[i][j]);
    }

    // epilogue helpers (coalesced half-tile path): thread covers row srow6 of the
    // half, chunks c0/c1 (16B each); XOR-swizzle p = chunk ^ (row&15) both sides.
    f16* As16 = &As[0][0];   // 24KB region, half-tile uses 16KB
    f16* Bs16 = &Bs[0][0];
    const int srow6 = tid >> 3, cb = tid & 7;
    const int c0 = cb, c1 = 8 + cb;
    const int g0 = c0 ^ (srow6 & 15), g1 = c1 ^ (srow6 & 15);

    if (OUT == 1) {
        f16* C = (f16*)O0;
#pragma unroll
        for (int hf = 0; hf < 2; hf++) {
            __syncthreads();   // prior LDS use done
            if (wr == hf) {
#pragma unroll
                for (int j = 0; j < 2; j++) {
                    int lc = wc * 32 + j * 16 + fr;
                    float bv = bias[col0 + lc];
#pragma unroll
                    for (int i = 0; i < 4; i++)
#pragma unroll
                        for (int r = 0; r < 4; r++) {
                            int lr = i * 16 + fq * 4 + r;
                            int p = (lc >> 3) ^ (lr & 15);
                            Bs16[lr * 128 + p * 8 + (lc & 7)] =
                                (f16)fmaxf(acc[i][j][r] + bv, 0.f);
                        }
                }
            }
            __syncthreads();
            size_t grow = (size_t)(row0 + hf * 64 + srow6) * N + col0;
            *(f16x8*)&C[grow + g0 * 8] = *(const f16x8*)&Bs16[srow6 * 128 + c0 * 8];
            *(f16x8*)&C[grow + g1 * 8] = *(const f16x8*)&Bs16[srow6 * 128 + c1 * 8];
        }
    } else if (OUT == 2) {
        const float SCQ = 0.18033688011112042f;   // 0.125 * log2(e), folded into Q
        f16* Qo = (f16*)O0; f16* Ko = (f16*)O1; f16* Vo = (f16*)O2;
#pragma unroll
        for (int j = 0; j < 2; j++) {
            int gcol = col0 + wc * 32 + j * 16 + fr;
            if (gcol < 1024) {
                bool isQ = gcol < 512;
                f16* dst = isQ ? Qo : Ko;
                float sc = isQ ? SCQ : 1.0f;
                int cc = gcol & 511;
#pragma unroll
                for (int i = 0; i < 4; i++) {
                    int gr = row0 + wr * 64 + i * 16 + fq * 4;
#pragma unroll
                    for (int r = 0; r < 4; r++)
                        dst[(size_t)(gr + r) * 512 + cc] = (f16)(acc[i][j][r] * sc);
                }
            } else {
                int hh = (gcol - 1024) >> 6, v = gcol & 63;
#pragma unroll
                for (int i = 0; i < 4; i++) {
                    int gr = row0 + wr * 64 + i * 16 + fq * 4;
                    int b = gr >> 9, n = gr & 511;
                    f16x4 sv;
#pragma unroll
                    for (int r = 0; r < 4; r++) sv[r] = (f16)acc[i][j][r];
                    *(f16x4*)&Vo[(((size_t)b * 8 + hh) * 64 + v) * 512 + n] = sv;
                }
            }
        }
    } else {   // OUT == 3: f16 trunk residual + stats, coalesced via LDS halves
        f16* hres = (f16*)O0;
        float* st  = (float*)O1;
#pragma unroll
        for (int hf = 0; hf < 2; hf++) {
            __syncthreads();   // prior LDS use done
            size_t grow = (size_t)(row0 + hf * 64 + srow6) * N + col0;
            f16x8 t0 = *(const f16x8*)&hres[grow + g0 * 8];
            f16x8 t1 = *(const f16x8*)&hres[grow + g1 * 8];
            *(f16x8*)&As16[srow6 * 128 + c0 * 8] = t0;
            *(f16x8*)&As16[srow6 * 128 + c1 * 8] = t1;
            __syncthreads();
            if (wr == hf) {
#pragma unroll
                for (int j = 0; j < 2; j++) {
                    int lc = wc * 32 + j * 16 + fr;
                    int gcol = col0 + lc;
                    float bv = bias ? bias[gcol] : 0.f;
                    float csum = 0.f, csq = 0.f;
#pragma unroll
                    for (int i = 0; i < 4; i++)
#pragma unroll
                        for (int r = 0; r < 4; r++) {
                            int lr = i * 16 + fq * 4 + r;
                            int p = (lc >> 3) ^ (lr & 15);
                            float hold = (float)As16[lr * 128 + p * 8 + (lc & 7)];
                            float v = acc[i][j][r] + bv + hold;
                            Bs16[lr * 128 + p * 8 + (lc & 7)] = (f16)v;
                            csum += v; csq += v * v;
                        }
                    csum += __shfl_down(csum, 32, 64); csum += __shfl_down(csum, 16, 64);
                    csq  += __shfl_down(csq,  32, 64); csq  += __shfl_down(csq,  16, 64);
                    if (fq == 0) {
                        atomicAdd(&st[gcol], csum);
                        atomicAdd(&st[gcol + 512], csq);
                    }
                }
            }
            __syncthreads();
            *(f16x8*)&hres[grow + g0 * 8] = *(const f16x8*)&Bs16[srow6 * 128 + c0 * 8];
            *(f16x8*)&hres[grow + g1 * 8] = *(const f16x8*)&Bs16[srow6 * 128 + c1 * 8];
        }
    }
}

// ---------------- flash attention: 8 waves / 256 q-rows per block ----------------
__global__ __launch_bounds__(512, 4)
void attn_flash(const f16* __restrict__ Q, const f16* __restrict__ Kg,
                const f16* __restrict__ Vt, const u64* __restrict__ pmask,
                f16* __restrict__ attf) {
    int id = blockIdx.x;
    int wgid = (id & 7) * 64 + (id >> 3);   // bijective XCD swizzle (512 = 8*64)
    int qc = wgid & 1;
    int gid = wgid >> 1;
    int b = gid & 31, hd = gid >> 5;

    __shared__ f16 Kl[2][4096];     // [cg 0..7][row 0..63] x 8 f16
    __shared__ f16 Vl[2][4096];

    const int tid = threadIdx.x, w = tid >> 6, l = tid & 63;
    const int q = l & 31, hi = l >> 5;

    const int brow = qc * 256 + w * 32;
    const size_t qrow = ((size_t)b * NSEQ + brow + q) * DIM + hd * 64;
    f16x8 qb[4];
#pragma unroll
    for (int c16 = 0; c16 < 4; c16++)
        qb[c16] = *(const f16x8*)(Q + qrow + c16 * 16 + hi * 8);

    const f16* ksrc = Kg + (size_t)b * NSEQ * DIM + hd * 64;   // row stride DIM
    const f16* vsrc = Vt + ((size_t)b * 8 + hd) * 64 * 512;    // row stride 512
    const u64* mrowq = pmask + ((size_t)b * NSEQ + brow + q) * 8;

    const int srw = tid & 63, scg = tid >> 6;   // staging row / col-group

    const float THR = 11.0f;    // P <= 2^11, f16-safe
    float mu = -1e30f;
    f32x16 O0 = {}, O1 = {}, S1 = {};

    f16x8 vones;
#pragma unroll
    for (int i = 0; i < 8; i++) vones[i] = (f16)1.0f;

    gload_lds16(ksrc + (size_t)srw * DIM + scg * 8, &Kl[0][tid * 8]);
    gload_lds16(vsrc + (size_t)srw * 512 + scg * 8, &Vl[0][tid * 8]);

    u64 bits = mrowq[0];

    for (int c = 0; c < 8; c++) {
        const int buf = c & 1;
        __syncthreads();   // stage(c) landed; prior reads of buf^1 done
        if (c < 7) {
            const int n1 = (c + 1) * 64;
            gload_lds16(ksrc + (size_t)(n1 + srw) * DIM + scg * 8, &Kl[buf ^ 1][tid * 8]);
            gload_lds16(vsrc + (size_t)srw * 512 + n1 + scg * 8,   &Vl[buf ^ 1][tid * 8]);
        }

        f32x16 ps0 = {}, ps1 = {};
        __builtin_amdgcn_s_setprio(1);
#pragma unroll
        for (int c16 = 0; c16 < 4; c16++) {
            f16x8 kb0 = *(const f16x8*)&Kl[buf][((c16 * 2 + hi) * 64 + q) * 8];
            f16x8 kb1 = *(const f16x8*)&Kl[buf][((c16 * 2 + hi) * 64 + 32 + q) * 8];
            ps0 = mfma32(kb0, qb[c16], ps0);
            ps1 = mfma32(kb1, qb[c16], ps1);
        }
        __builtin_amdgcn_s_setprio(0);

        unsigned blo = (unsigned)bits, bhi = (unsigned)(bits >> 32);
        if (c < 7) bits = mrowq[c + 1];   // prefetch next mask word

        float lm = fmaxf(ps0[0], ps1[0]);
#pragma unroll
        for (int r = 1; r < 16; r++) lm = fmaxf(lm, fmaxf(ps0[r], ps1[r]));
        if (__any(lm > mu + THR)) {
            float other = __shfl_xor(lm, 32, 64);
            float mn = fmaxf(mu, fmaxf(lm, other));
            float sc = exp2f(mu - mn);
            mu = mn;
            S1 *= sc; O0 *= sc; O1 *= sc;
        }

        float p0[16], p1[16];
#pragma unroll
        for (int r = 0; r < 16; r++) {
            int n0 = (r & 3) + 8 * (r >> 2) + 4 * hi;
            float e0 = exp2f(ps0[r] - mu);
            float e1 = exp2f(ps1[r] - mu);
            unsigned k0 = ((blo >> n0) & 1u) - 1u;   // 0xFFFFFFFF keep, 0 zero
            unsigned k1 = ((bhi >> n0) & 1u) - 1u;
            p0[r] = __uint_as_float(__float_as_uint(e0) & k0);
            p1[r] = __uint_as_float(__float_as_uint(e1) & k1);
        }

        f16x8 PA[2][2];
#pragma unroll
        for (int ntile = 0; ntile < 2; ntile++) {
            const float* p = ntile ? p1 : p0;
#pragma unroll
            for (int m = 0; m < 2; m++) {
                unsigned a0 = pk2u(p[m * 8 + 0], p[m * 8 + 1]);
                unsigned b0 = pk2u(p[m * 8 + 4], p[m * 8 + 5]);
                auto s0 = __builtin_amdgcn_permlane32_swap(a0, b0, false, false);
                unsigned a1 = pk2u(p[m * 8 + 2], p[m * 8 + 3]);
                unsigned b1 = pk2u(p[m * 8 + 6], p[m * 8 + 7]);
                auto s1 = __builtin_amdgcn_permlane32_swap(a1, b1, false, false);
                unsigned wbuf[4] = {(unsigned)s0[0], (unsigned)s1[0],
                                    (unsigned)s0[1], (unsigned)s1[1]};
                PA[ntile][m] = *reinterpret_cast<f16x8*>(wbuf);
            }
        }

        __builtin_amdgcn_s_setprio(1);
#pragma unroll
        for (int ntile = 0; ntile < 2; ntile++)
#pragma unroll
            for (int m = 0; m < 2; m++) {
                f16x8 pa = PA[ntile][m];
                S1 = mfma32(vones, pa, S1);
                int cg = ntile * 4 + m * 2 + hi;
                f16x8 v0 = *(const f16x8*)&Vl[buf][(cg * 64 + q) * 8];
                f16x8 v1 = *(const f16x8*)&Vl[buf][(cg * 64 + 32 + q) * 8];
                O0 = mfma32(v0, pa, O0);
                O1 = mfma32(v1, pa, O1);
            }
        __builtin_amdgcn_s_setprio(0);
    }

    float inv = 1.f / S1[0];
    f16* orow = attf + ((size_t)b * NSEQ + brow + q) * DIM + hd * 64;
#pragma unroll
    for (int r = 0; r < 16; r += 2) {
        int v = (r & 3) + 8 * (r >> 2) + 4 * hi;
        unsigned w0 = pk2u(O0[r] * inv, O0[r + 1] * inv);
        *(unsigned*)(orow + v) = w0;
        unsigned w1 = pk2u(O1[r] * inv, O1[r + 1] * inv);
        *(unsigned*)(orow + 32 + v) = w1;
    }
}

// ---------------- BN apply on f16 trunk (vectorized x8) ----------------
__global__ __launch_bounds__(256)
void bn_apply(f16* __restrict__ h16, const float* __restrict__ sums,
              const float* __restrict__ g, const float* __restrict__ bt,
              float* __restrict__ outp) {
    size_t i8 = (size_t)blockIdx.x * 256 + threadIdx.x;
    size_t idx = i8 * 8;
    int c = (int)(idx & (DIM - 1));
    f16x8 hv = *(f16x8*)&h16[idx];
    float o[8];
    const float invn = 1.f / BN_ROWS;
#pragma unroll
    for (int j = 0; j < 8; j++) {
        float mu = sums[c + j] * invn;
        float var = sums[DIM + c + j] * invn - mu * mu;
        o[j] = ((float)hv[j] - mu) * rsqrtf(var + 1e-5f) * g[c + j] + bt[c + j];
    }
    f16x8 s;
#pragma unroll
    for (int j = 0; j < 8; j++) s[j] = (f16)o[j];
    *(f16x8*)&h16[idx] = s;
    if (outp) {
        *(float4*)&outp[idx]     = (float4){o[0], o[1], o[2], o[3]};
        *(float4*)&outp[idx + 4] = (float4){o[4], o[5], o[6], o[7]};
    }
}

// ---------------- mean over n ----------------
__global__ __launch_bounds__(512)
void mean_kernel(const float* __restrict__ src, float* __restrict__ out2) {
    int b = blockIdx.x, seg = blockIdx.y, d = threadIdx.x;
    float acc = 0.f;
    for (int n = seg * 64; n < seg * 64 + 64; n++)
        acc += src[((size_t)b * NSEQ + n) * DIM + d];
    atomicAdd(&out2[b * DIM + d], acc * (1.f / NSEQ));
}

extern "C" void kernel_launch(void* const* d_in, const int* in_sizes, int n_in,
                              void* d_out, int out_size, void* d_ws, size_t ws_size,
                              hipStream_t stream) {
    const float* x   = (const float*)d_in[0];
    const int*   mask= (const int*)d_in[1];
    const float* We  = (const float*)d_in[2];
    const float* be  = (const float*)d_in[3];
    const float* Wq  = (const float*)d_in[4];
    const float* Wk  = (const float*)d_in[5];
    const float* Wv  = (const float*)d_in[6];
    const float* Wo  = (const float*)d_in[7];
    const float* g1  = (const float*)d_in[8];
    const float* bt1 = (const float*)d_in[9];
    const float* g2  = (const float*)d_in[10];
    const float* bt2 = (const float*)d_in[11];
    const float* W1  = (const float*)d_in[12];
    const float* bf1 = (const float*)d_in[13];
    const float* W2  = (const float*)d_in[14];
    const float* bf2 = (const float*)d_in[15];
    float* out = (float*)d_out;

    const size_t MiB = 1ull << 20;
    const size_t M1 = (size_t)BN_ROWS * DIM;
    char* base = (char*)d_ws;
    f16*   h16   = (f16*)base;                      // 0-16 MiB (f16 trunk)
    f16*   Qf    = (f16*)(base + 16 * MiB);
    f16*   Kf    = (f16*)(base + 32 * MiB);
    f16*   Vt    = (f16*)(base + 48 * MiB);
    f16*   attf  = (f16*)(base + 64 * MiB);
    f16*   ffh   = (f16*)(base + 16 * MiB);         // 64 MiB, reuses Qf..attf (dead by FFN)
    float* stats = (float*)(base + 80 * MiB);       // 8 slots x 1024 floats = 32 KiB
    u64*   pmask = (u64*)(base + 80 * MiB + 65536); // 1 MiB
    f16*   wqkv  = (f16*)(base + 82 * MiB);         // 12.6 MiB
    f16*   wo    = wqkv + (size_t)4 * 1536 * 512;   // 2.1
    f16*   w1t   = wo   + (size_t)4 * 512 * 512;    // 8.4
    f16*   w2t   = w1t  + (size_t)4 * 2048 * 512;   // 8.4

    pack_qkv<<<dim3(4 * 1536 * 512 / 256), dim3(256), 0, stream>>>(Wq, Wk, Wv, wqkv);
    transpose_w<<<dim3(4 * 512 * 512 / 256), dim3(256), 0, stream>>>(Wo, wo, 512, 512);
    transpose_w<<<dim3(4 * 512 * 2048 / 256), dim3(256), 0, stream>>>(W1, w1t, 512, 2048);
    transpose_w<<<dim3(4 * 2048 * 512 / 256), dim3(256), 0, stream>>>(W2, w2t, 2048, 512);
    pack_mask<<<dim3(512), dim3(256), 0, stream>>>(mask, pmask);
    hipMemsetAsync(stats, 0, 8 * 1024 * sizeof(float), stream);   // all BN slots, once
    hipMemsetAsync(out + M1, 0, BATCH * DIM * sizeof(float), stream);

    embed_kernel<<<dim3(BN_ROWS), dim3(512), 0, stream>>>(x, We, be, h16);

    for (int l = 0; l < LAYERS; l++) {
        float* st1 = stats + (size_t)(l * 2 + 0) * 1024;
        float* st2 = stats + (size_t)(l * 2 + 1) * 1024;

        gemm_f16<2><<<dim3(1536 / 128, 128), dim3(512), 0, stream>>>(
            h16, wqkv + (size_t)l * 1536 * 512, nullptr, Qf, Kf, Vt,
            BN_ROWS, 1536, 512);

        attn_flash<<<dim3(512), dim3(512), 0, stream>>>(Qf, Kf, Vt, pmask, attf);

        gemm_f16<3><<<dim3(512 / 128, 128), dim3(512), 0, stream>>>(
            attf, wo + (size_t)l * 512 * 512, nullptr, h16, st1, nullptr,
            BN_ROWS, 512, 512);
        bn_apply<<<dim3(M1 / 2048), dim3(256), 0, stream>>>(
            h16, st1, g1 + l * DIM, bt1 + l * DIM, nullptr);

        gemm_f16<1><<<dim3(FF / 128, BN_ROWS / 128), dim3(512), 0, stream>>>(
            h16, w1t + (size_t)l * FF * DIM, bf1 + (size_t)l * FF,
            ffh, nullptr, nullptr, BN_ROWS, FF, DIM);
        gemm_f16<3><<<dim3(512 / 128, 128), dim3(512), 0, stream>>>(
            ffh, w2t + (size_t)l * DIM * FF, bf2 + (size_t)l * DIM,
            h16, st2, nullptr, BN_ROWS, 512, FF);

        float* outp = (l == LAYERS - 1) ? out : nullptr;
        bn_apply<<<dim3(M1 / 2048), dim3(256), 0, stream>>>(
            h16, st2, g2 + l * DIM, bt2 + l * DIM, outp);
    }

    mean_kernel<<<dim3(BATCH, 8), dim3(512), 0, stream>>>(out, out + M1);
}